// Round 5
// baseline (133.638 us; speedup 1.0000x reference)
//
#include <hip/hip_runtime.h>
#include <math.h>

// Level geometry (fixed by reference: strides 4/8/16, H=W=160/80/40)
#define NL0 25600   // 160*160
#define NL1 6400    // 80*80
#define NL2 1600    // 40*40
#define NTOT 33600
#define MAXM 64
#define ANCH 2      // anchors per thread (level bases & row widths even)
#define TPB 256
#define CHUNK 8     // boxes per scalar-load batch

__device__ __forceinline__ float logsig(float x) {
    // numerically stable log(sigmoid(x))
    return fminf(x, 0.0f) - log1pf(expf(-fabsf(x)));
}

// acc layout in d_ws: [cls_sum, reg_sum, npos, done_counter(uint)]
__global__ __launch_bounds__(TPB, 1) void fcos_main(
    const float* __restrict__ cls0, const float* __restrict__ cls1,
    const float* __restrict__ cls2, const float* __restrict__ reg0,
    const float* __restrict__ reg1, const float* __restrict__ reg2,
    const float* __restrict__ boxes, int M, float* __restrict__ acc,
    float* __restrict__ out, int B)
{
    const int b = blockIdx.y;
    const int base = (blockIdx.x * TPB + threadIdx.x) * ANCH;

    // LDS copy of boxes used ONLY for the epilogue's divergent gather.
    __shared__ float4 sbox[MAXM];
    if (threadIdx.x < MAXM) {
        const int j = threadIdx.x;
        sbox[j] = (j < M) ? ((const float4*)boxes)[(size_t)b * M + j]
                          : make_float4(0.f, 0.f, 0.f, 0.f);
    }
    __syncthreads();

    float clsl = 0.0f, regl = 0.0f, posf = 0.0f;

    if (base < NTOT) {
        int ii, hw;
        float s, low, high, x0, y;
        const float* cbase;
        const float* rbase;
        if (base < NL0) {
            ii = base; hw = NL0; s = 4.0f; low = -1.0f; high = 64.0f;
            cbase = cls0; rbase = reg0;
            const int h = ii / 160, w = ii - h * 160;
            x0 = ((float)w + 0.5f) * s; y = ((float)h + 0.5f) * s;
        } else if (base < NL0 + NL1) {
            ii = base - NL0; hw = NL1; s = 8.0f; low = 64.0f; high = 128.0f;
            cbase = cls1; rbase = reg1;
            const int h = ii / 80, w = ii - h * 80;
            x0 = ((float)w + 0.5f) * s; y = ((float)h + 0.5f) * s;
        } else {
            ii = base - (NL0 + NL1); hw = NL2; s = 16.0f; low = 128.0f; high = 99999.0f;
            cbase = cls2; rbase = reg2;
            const int h = ii / 40, w = ii - h * 40;
            x0 = ((float)w + 0.5f) * s; y = ((float)h + 0.5f) * s;
        }
        const float xk[ANCH] = { x0, x0 + s };

        // Hoist epilogue global loads so their latency overlaps the M-loop.
        const float* rp = rbase + (size_t)b * 4 * hw + ii;
        const float2 pl2 = *(const float2*)(rp);
        const float2 pt2 = *(const float2*)(rp + hw);
        const float2 pr2 = *(const float2*)(rp + 2 * hw);
        const float2 pb2 = *(const float2*)(rp + 3 * hw);
        const float2 lg2 = *(const float2*)(cbase + (size_t)b * hw + ii);
        const float plv[2] = { pl2.x, pl2.y };
        const float ptv[2] = { pt2.x, pt2.y };
        const float prv[2] = { pr2.x, pr2.y };
        const float pbv[2] = { pb2.x, pb2.y };
        const float lgv[2] = { lg2.x, lg2.y };

        unsigned best[ANCH] = { 0xFFFFFFFFu, 0xFFFFFFFFu };

        // Wave-uniform base: all indices below are uniform -> scalar (s_load)
        // path through the constant cache; box coords live in SGPRs, the
        // M-loop is pure VALU with no per-iteration LDS/VMEM latency.
        const float* bp = boxes + (size_t)b * 4 * M;

        #pragma unroll 1
        for (int j0 = 0; j0 < MAXM; j0 += CHUNK) {
            float bxx[CHUNK], bxy[CHUNK], bxz[CHUNK], bxw[CHUNK];
            unsigned pk[CHUNK];
            #pragma unroll
            for (int u = 0; u < CHUNK; ++u) {
                const int j = j0 + u;
                const int jc = (j < M) ? j : (M - 1);   // uniform clamp, no OOB
                bxx[u] = bp[4 * jc + 0];
                bxy[u] = bp[4 * jc + 1];
                bxz[u] = bp[4 * jc + 2];
                bxw[u] = bp[4 * jc + 3];
                const float area = (bxz[u] - bxx[u]) * (bxw[u] - bxy[u]);
                const unsigned key = (__float_as_uint(area) & ~63u) | (unsigned)j;
                pk[u] = (j < M) ? key : 0xFFFFFFFFu;
            }
            #pragma unroll
            for (int u = 0; u < CHUNK; ++u) {
                const float t  = y - bxy[u];
                const float bo = bxw[u] - y;
                const float mtb = fminf(t, bo);
                const float xtb = fmaxf(t, bo);
                const float l0 = x0 - bxx[u];
                const float r0 = bxz[u] - x0;
                #pragma unroll
                for (int k = 0; k < ANCH; ++k) {
                    const float ks = (float)k * s;
                    const float l = l0 + ks;
                    const float r = r0 - ks;
                    const float mn = fminf(fminf(l, r), mtb);
                    const float mx = fmaxf(fmaxf(l, r), xtb);
                    const bool ok = (mn > 0.0f) & (mx > low) & (mx < high);
                    const unsigned cand = ok ? pk[u] : 0xFFFFFFFFu;
                    best[k] = min(best[k], cand);
                }
            }
        }

        #pragma unroll
        for (int k = 0; k < ANCH; ++k) {
            const bool pos = (best[k] != 0xFFFFFFFFu);
            const int idx = (int)(best[k] & 63u);
            const float4 tbx = sbox[idx];       // divergent gather, 1/anchor
            const float xc = xk[k];
            const float tl = xc - tbx.x, tt = y - tbx.y;
            const float tr = tbx.z - xc, tb = tbx.w - y;

            const float pl = plv[k], pt = ptv[k], pr = prv[k], pb = pbv[k];

            const float w_i = fminf(pl, tl) + fminf(pr, tr);
            const float h_i = fminf(pt, tt) + fminf(pb, tb);
            const float a_i = fmaxf(w_i, 0.0f) * fmaxf(h_i, 0.0f);
            const float a_p = (pl + pr) * (pt + pb);
            const float a_t = (tl + tr) * (tt + tb);
            const float a_u = a_p + a_t - a_i + 1e-7f;
            const float iou_raw = a_i / a_u;

            const float w_e = fmaxf(pl, tl) + fmaxf(pr, tr);
            const float h_e = fmaxf(pt, tt) + fmaxf(pb, tb);
            const float a_e = fmaxf(w_e, 0.0f) * fmaxf(h_e, 0.0f) + 1e-7f;
            const float gl = 1.0f - (iou_raw - (a_e - a_u) / a_e);

            regl += pos ? gl : 0.0f;
            posf += pos ? 1.0f : 0.0f;
            const float gt_iou = pos ? fminf(fmaxf(iou_raw, 0.0f), 1.0f) : 0.0f;

            const float logit = lgv[k];
            const float p = 1.0f / (1.0f + expf(-logit));
            const float log_p  = logsig(logit);
            const float log_np = logsig(-logit);
            if (gt_iou > 0.0f)
                clsl += -gt_iou * (gt_iou * log_p + (1.0f - gt_iou) * log_np);
            else
                clsl += -0.75f * p * p * log_np;
        }
    }

    // block reduction: wave shuffle (width 64) then cross-wave via LDS
    float v0 = clsl, v1 = regl, v2 = posf;
    #pragma unroll
    for (int off = 32; off > 0; off >>= 1) {
        v0 += __shfl_down(v0, off);
        v1 += __shfl_down(v1, off);
        v2 += __shfl_down(v2, off);
    }
    __shared__ float red[3][TPB / 64];
    const int lane = threadIdx.x & 63;
    const int wv   = threadIdx.x >> 6;
    if (lane == 0) { red[0][wv] = v0; red[1][wv] = v1; red[2][wv] = v2; }
    __syncthreads();
    if (threadIdx.x == 0) {
        float s0 = 0, s1 = 0, s2 = 0;
        #pragma unroll
        for (int wvi = 0; wvi < TPB / 64; ++wvi) { s0 += red[0][wvi]; s1 += red[1][wvi]; s2 += red[2][wvi]; }
        atomicAdd(&acc[0], s0);
        atomicAdd(&acc[1], s1);
        atomicAdd(&acc[2], s2);
        __threadfence();
        const unsigned total = gridDim.x * gridDim.y;
        const unsigned old = atomicAdd((unsigned*)&acc[3], 1u);
        if (old == total - 1u) {
            // last block: all other blocks' atomics are globally visible
            const float cls_sum = atomicAdd(&acc[0], 0.0f);
            const float reg_sum = atomicAdd(&acc[1], 0.0f);
            const float npos    = atomicAdd(&acc[2], 0.0f);
            const float navg = fmaxf(1.0f, npos / (float)B);
            out[0] = (cls_sum + reg_sum) / navg;
            out[1] = cls_sum / navg;
            out[2] = reg_sum / navg;
        }
    }
}

extern "C" void kernel_launch(void* const* d_in, const int* in_sizes, int n_in,
                              void* d_out, int out_size, void* d_ws, size_t ws_size,
                              hipStream_t stream) {
    const float* cls0 = (const float*)d_in[0];
    const float* cls1 = (const float*)d_in[1];
    const float* cls2 = (const float*)d_in[2];
    const float* reg0 = (const float*)d_in[3];
    const float* reg1 = (const float*)d_in[4];
    const float* reg2 = (const float*)d_in[5];
    const float* boxes = (const float*)d_in[6];

    const int B = in_sizes[0] / NL0;          // 16
    const int M = in_sizes[6] / (4 * B);      // 64 (<= MAXM)

    float* acc = (float*)d_ws;                // [cls_sum, reg_sum, npos, counter]

    hipMemsetAsync(acc, 0, 4 * sizeof(float), stream);
    dim3 grid((NTOT / ANCH + TPB - 1) / TPB, B);
    fcos_main<<<grid, TPB, 0, stream>>>(cls0, cls1, cls2, reg0, reg1, reg2,
                                        boxes, M, acc, (float*)d_out, B);
}

// Round 6
// 90.113 us; speedup vs baseline: 1.4830x; 1.4830x over previous
//
#include <hip/hip_runtime.h>
#include <math.h>

// Level geometry (fixed by reference: strides 4/8/16, H=W=160/80/40)
#define NL0 25600   // 160*160
#define NL1 6400    // 80*80
#define NL2 1600    // 40*40
#define NTOT 33600
#define MAXM 64
#define ANCH 4      // anchors per thread (level bases & row widths divisible by 4)
#define TPB 256
#define GX 33       // ceil(NTOT / (ANCH*TPB)) blocks per image
#define NB 16       // batch
#define NPART (GX * NB)   // 528 partial slots

__device__ __forceinline__ float logsig(float x) {
    // numerically stable log(sigmoid(x))
    return fminf(x, 0.0f) - log1pf(expf(-fabsf(x)));
}

// ws layout (floats): cls_part[NPART] | reg_part[NPART] | pos_part[NPART]
// NO global atomics anywhere: per-block plain stores to distinct addresses.
// (Theory R5: duration was dominated by ~60ns/block of serialized
//  same-cacheline atomic RMWs, not by the M-loop.)
__global__ __launch_bounds__(TPB, 1) void fcos_main(
    const float* __restrict__ cls0, const float* __restrict__ cls1,
    const float* __restrict__ cls2, const float* __restrict__ reg0,
    const float* __restrict__ reg1, const float* __restrict__ reg2,
    const float* __restrict__ boxes, int M, float* __restrict__ part)
{
    const int b = blockIdx.y;
    const int base = (blockIdx.x * TPB + threadIdx.x) * ANCH;

    __shared__ float4 sbox[MAXM];      // x0,y0,x1,y1 (padded with dummies)
    __shared__ unsigned spk[MAXM];     // (area_bits & ~63) | j  -- argmin key

    if (threadIdx.x < MAXM) {
        const int j = threadIdx.x;
        if (j < M) {
            float4 bx = ((const float4*)boxes)[(size_t)b * M + j];
            sbox[j] = bx;
            const float area = (bx.z - bx.x) * (bx.w - bx.y);
            spk[j] = (__float_as_uint(area) & ~63u) | (unsigned)j;
        } else {
            sbox[j] = make_float4(0.f, 0.f, 0.f, 0.f);  // never matches (r<0)
            spk[j] = 0xFFFFFFFFu;
        }
    }
    __syncthreads();

    float clsl = 0.0f, regl = 0.0f, posf = 0.0f;

    if (base < NTOT) {
        int ii, hw;
        float s, low, high, x0, y;
        const float* cbase;
        const float* rbase;
        if (base < NL0) {
            ii = base; hw = NL0; s = 4.0f; low = -1.0f; high = 64.0f;
            cbase = cls0; rbase = reg0;
            const int h = ii / 160, w = ii - h * 160;
            x0 = ((float)w + 0.5f) * s; y = ((float)h + 0.5f) * s;
        } else if (base < NL0 + NL1) {
            ii = base - NL0; hw = NL1; s = 8.0f; low = 64.0f; high = 128.0f;
            cbase = cls1; rbase = reg1;
            const int h = ii / 80, w = ii - h * 80;
            x0 = ((float)w + 0.5f) * s; y = ((float)h + 0.5f) * s;
        } else {
            ii = base - (NL0 + NL1); hw = NL2; s = 16.0f; low = 128.0f; high = 99999.0f;
            cbase = cls2; rbase = reg2;
            const int h = ii / 40, w = ii - h * 40;
            x0 = ((float)w + 0.5f) * s; y = ((float)h + 0.5f) * s;
        }
        const float xk[ANCH] = { x0, x0 + s, x0 + 2.0f * s, x0 + 3.0f * s };

        // Hoist epilogue global loads so their latency overlaps the M-loop.
        const float* rp = rbase + (size_t)b * 4 * hw + ii;
        const float4 pl4 = *(const float4*)(rp);
        const float4 pt4 = *(const float4*)(rp + hw);
        const float4 pr4 = *(const float4*)(rp + 2 * hw);
        const float4 pb4 = *(const float4*)(rp + 3 * hw);
        const float4 lg4 = *(const float4*)(cbase + (size_t)b * hw + ii);
        const float* plv = (const float*)&pl4;
        const float* ptv = (const float*)&pt4;
        const float* prv = (const float*)&pr4;
        const float* pbv = (const float*)&pb4;
        const float* lgv = (const float*)&lg4;

        unsigned best[ANCH] = { 0xFFFFFFFFu, 0xFFFFFFFFu, 0xFFFFFFFFu, 0xFFFFFFFFu };

        #pragma unroll 4
        for (int j = 0; j < MAXM; ++j) {
            const float4 bx = sbox[j];          // broadcast ds_read_b128
            const unsigned pk = spk[j];
            const float t  = y - bx.y;
            const float bo = bx.w - y;
            const float mtb = fminf(t, bo);
            const float xtb = fmaxf(t, bo);
            const float l0 = x0 - bx.x;
            const float r0 = bx.z - x0;
            #pragma unroll
            for (int k = 0; k < ANCH; ++k) {
                const float ks = (float)k * s;
                const float l = l0 + ks;
                const float r = r0 - ks;
                const float mn = fminf(fminf(l, r), mtb);
                const float mx = fmaxf(fmaxf(l, r), xtb);
                const bool ok = (mn > 0.0f) & (mx > low) & (mx < high);
                const unsigned cand = ok ? pk : 0xFFFFFFFFu;
                best[k] = min(best[k], cand);
            }
        }

        #pragma unroll
        for (int k = 0; k < ANCH; ++k) {
            const bool pos = (best[k] != 0xFFFFFFFFu);
            const int idx = (int)(best[k] & 63u);
            const float4 tbx = sbox[idx];       // divergent gather, 1/anchor
            const float xc = xk[k];
            const float tl = xc - tbx.x, tt = y - tbx.y;
            const float tr = tbx.z - xc, tb = tbx.w - y;

            const float pl = plv[k], pt = ptv[k], pr = prv[k], pb = pbv[k];

            const float w_i = fminf(pl, tl) + fminf(pr, tr);
            const float h_i = fminf(pt, tt) + fminf(pb, tb);
            const float a_i = fmaxf(w_i, 0.0f) * fmaxf(h_i, 0.0f);
            const float a_p = (pl + pr) * (pt + pb);
            const float a_t = (tl + tr) * (tt + tb);
            const float a_u = a_p + a_t - a_i + 1e-7f;
            const float iou_raw = a_i / a_u;

            const float w_e = fmaxf(pl, tl) + fmaxf(pr, tr);
            const float h_e = fmaxf(pt, tt) + fmaxf(pb, tb);
            const float a_e = fmaxf(w_e, 0.0f) * fmaxf(h_e, 0.0f) + 1e-7f;
            const float gl = 1.0f - (iou_raw - (a_e - a_u) / a_e);

            regl += pos ? gl : 0.0f;
            posf += pos ? 1.0f : 0.0f;
            const float gt_iou = pos ? fminf(fmaxf(iou_raw, 0.0f), 1.0f) : 0.0f;

            const float logit = lgv[k];
            const float p = 1.0f / (1.0f + expf(-logit));
            const float log_p  = logsig(logit);
            const float log_np = logsig(-logit);
            if (gt_iou > 0.0f)
                clsl += -gt_iou * (gt_iou * log_p + (1.0f - gt_iou) * log_np);
            else
                clsl += -0.75f * p * p * log_np;
        }
    }

    // block reduction: wave shuffle (width 64) then cross-wave via LDS
    float v0 = clsl, v1 = regl, v2 = posf;
    #pragma unroll
    for (int off = 32; off > 0; off >>= 1) {
        v0 += __shfl_down(v0, off);
        v1 += __shfl_down(v1, off);
        v2 += __shfl_down(v2, off);
    }
    __shared__ float red[3][TPB / 64];
    const int lane = threadIdx.x & 63;
    const int wv   = threadIdx.x >> 6;
    if (lane == 0) { red[0][wv] = v0; red[1][wv] = v1; red[2][wv] = v2; }
    __syncthreads();
    if (threadIdx.x == 0) {
        float s0 = 0, s1 = 0, s2 = 0;
        #pragma unroll
        for (int wvi = 0; wvi < TPB / 64; ++wvi) { s0 += red[0][wvi]; s1 += red[1][wvi]; s2 += red[2][wvi]; }
        // plain stores to distinct addresses -- no serialization, no atomics
        const int p = blockIdx.y * GX + blockIdx.x;
        part[p]             = s0;
        part[NPART + p]     = s1;
        part[2 * NPART + p] = s2;
    }
}

__global__ __launch_bounds__(TPB) void fcos_final(
    const float* __restrict__ part, float* __restrict__ out, int B)
{
    float s0 = 0.0f, s1 = 0.0f, s2 = 0.0f;
    for (int i = threadIdx.x; i < NPART; i += TPB) {
        s0 += part[i];
        s1 += part[NPART + i];
        s2 += part[2 * NPART + i];
    }
    #pragma unroll
    for (int off = 32; off > 0; off >>= 1) {
        s0 += __shfl_down(s0, off);
        s1 += __shfl_down(s1, off);
        s2 += __shfl_down(s2, off);
    }
    __shared__ float red[3][TPB / 64];
    const int lane = threadIdx.x & 63;
    const int wv   = threadIdx.x >> 6;
    if (lane == 0) { red[0][wv] = s0; red[1][wv] = s1; red[2][wv] = s2; }
    __syncthreads();
    if (threadIdx.x == 0) {
        float cls_sum = 0, reg_sum = 0, npos = 0;
        #pragma unroll
        for (int wvi = 0; wvi < TPB / 64; ++wvi) {
            cls_sum += red[0][wvi]; reg_sum += red[1][wvi]; npos += red[2][wvi];
        }
        const float navg = fmaxf(1.0f, npos / (float)B);
        out[0] = (cls_sum + reg_sum) / navg;
        out[1] = cls_sum / navg;
        out[2] = reg_sum / navg;
    }
}

extern "C" void kernel_launch(void* const* d_in, const int* in_sizes, int n_in,
                              void* d_out, int out_size, void* d_ws, size_t ws_size,
                              hipStream_t stream) {
    const float* cls0 = (const float*)d_in[0];
    const float* cls1 = (const float*)d_in[1];
    const float* cls2 = (const float*)d_in[2];
    const float* reg0 = (const float*)d_in[3];
    const float* reg1 = (const float*)d_in[4];
    const float* reg2 = (const float*)d_in[5];
    const float* boxes = (const float*)d_in[6];

    const int B = in_sizes[0] / NL0;          // 16
    const int M = in_sizes[6] / (4 * B);      // 64 (<= MAXM)

    float* part = (float*)d_ws;               // 3 * NPART floats

    dim3 grid(GX, B);
    fcos_main<<<grid, TPB, 0, stream>>>(cls0, cls1, cls2, reg0, reg1, reg2,
                                        boxes, M, part);
    fcos_final<<<1, TPB, 0, stream>>>(part, (float*)d_out, B);
}

// Round 7
// 87.897 us; speedup vs baseline: 1.5204x; 1.0252x over previous
//
#include <hip/hip_runtime.h>
#include <math.h>

// Level geometry (fixed by reference: strides 4/8/16, H=W=160/80/40)
#define NL0 25600   // 160*160
#define NL1 6400    // 80*80
#define NL2 1600    // 40*40
#define NTOT 33600
#define MAXM 64
#define ANCH 2      // anchors per thread: 4.1 waves/SIMD for LDS-latency cover
#define TPB 256
#define GX 66       // ceil(NTOT / (ANCH*TPB)) blocks per image
#define NB 16       // batch
#define NPART (GX * NB)   // 1056 partial slots

__device__ __forceinline__ float logsig(float x) {
    // numerically stable log(sigmoid(x))
    return fminf(x, 0.0f) - log1pf(expf(-fabsf(x)));
}

// ws layout (floats): cls_part[NPART] | reg_part[NPART] | pos_part[NPART]
// NO global atomics anywhere: per-block plain stores to distinct addresses.
// (R5 post-mortem: ~60ns/block of serialized same-cacheline atomic RMWs
//  dominated every round R1-R5; removing them was the R6 win.)
__global__ __launch_bounds__(TPB, 1) void fcos_main(
    const float* __restrict__ cls0, const float* __restrict__ cls1,
    const float* __restrict__ cls2, const float* __restrict__ reg0,
    const float* __restrict__ reg1, const float* __restrict__ reg2,
    const float* __restrict__ boxes, int M, float* __restrict__ part)
{
    const int b = blockIdx.y;
    const int base = (blockIdx.x * TPB + threadIdx.x) * ANCH;

    __shared__ float4 sbox[MAXM];      // x0,y0,x1,y1 (padded with dummies)
    __shared__ unsigned spk[MAXM];     // (area_bits & ~63) | j  -- argmin key

    if (threadIdx.x < MAXM) {
        const int j = threadIdx.x;
        if (j < M) {
            float4 bx = ((const float4*)boxes)[(size_t)b * M + j];
            sbox[j] = bx;
            const float area = (bx.z - bx.x) * (bx.w - bx.y);
            spk[j] = (__float_as_uint(area) & ~63u) | (unsigned)j;
        } else {
            sbox[j] = make_float4(0.f, 0.f, 0.f, 0.f);  // never matches (r<0)
            spk[j] = 0xFFFFFFFFu;
        }
    }
    __syncthreads();

    float clsl = 0.0f, regl = 0.0f, posf = 0.0f;

    if (base < NTOT) {
        int ii, hw;
        float s, low, high, x0, y;
        const float* cbase;
        const float* rbase;
        if (base < NL0) {
            ii = base; hw = NL0; s = 4.0f; low = -1.0f; high = 64.0f;
            cbase = cls0; rbase = reg0;
            const int h = ii / 160, w = ii - h * 160;
            x0 = ((float)w + 0.5f) * s; y = ((float)h + 0.5f) * s;
        } else if (base < NL0 + NL1) {
            ii = base - NL0; hw = NL1; s = 8.0f; low = 64.0f; high = 128.0f;
            cbase = cls1; rbase = reg1;
            const int h = ii / 80, w = ii - h * 80;
            x0 = ((float)w + 0.5f) * s; y = ((float)h + 0.5f) * s;
        } else {
            ii = base - (NL0 + NL1); hw = NL2; s = 16.0f; low = 128.0f; high = 99999.0f;
            cbase = cls2; rbase = reg2;
            const int h = ii / 40, w = ii - h * 40;
            x0 = ((float)w + 0.5f) * s; y = ((float)h + 0.5f) * s;
        }
        const float xk[ANCH] = { x0, x0 + s };

        // Hoist epilogue global loads so their latency overlaps the M-loop.
        const float* rp = rbase + (size_t)b * 4 * hw + ii;
        const float2 pl2 = *(const float2*)(rp);
        const float2 pt2 = *(const float2*)(rp + hw);
        const float2 pr2 = *(const float2*)(rp + 2 * hw);
        const float2 pb2 = *(const float2*)(rp + 3 * hw);
        const float2 lg2 = *(const float2*)(cbase + (size_t)b * hw + ii);
        const float plv[2] = { pl2.x, pl2.y };
        const float ptv[2] = { pt2.x, pt2.y };
        const float prv[2] = { pr2.x, pr2.y };
        const float pbv[2] = { pb2.x, pb2.y };
        const float lgv[2] = { lg2.x, lg2.y };

        unsigned best[ANCH] = { 0xFFFFFFFFu, 0xFFFFFFFFu };

        #pragma unroll 4
        for (int j = 0; j < MAXM; ++j) {
            const float4 bx = sbox[j];          // broadcast ds_read_b128
            const unsigned pk = spk[j];
            const float t  = y - bx.y;
            const float bo = bx.w - y;
            const float mtb = fminf(t, bo);
            const float xtb = fmaxf(t, bo);
            const float l0 = x0 - bx.x;
            const float r0 = bx.z - x0;
            #pragma unroll
            for (int k = 0; k < ANCH; ++k) {
                const float ks = (float)k * s;
                const float l = l0 + ks;
                const float r = r0 - ks;
                const float mn = fminf(fminf(l, r), mtb);
                const float mx = fmaxf(fmaxf(l, r), xtb);
                const bool ok = (mn > 0.0f) & (mx > low) & (mx < high);
                const unsigned cand = ok ? pk : 0xFFFFFFFFu;
                best[k] = min(best[k], cand);
            }
        }

        #pragma unroll
        for (int k = 0; k < ANCH; ++k) {
            const bool pos = (best[k] != 0xFFFFFFFFu);
            const int idx = (int)(best[k] & 63u);
            const float4 tbx = sbox[idx];       // divergent gather, 1/anchor
            const float xc = xk[k];
            const float tl = xc - tbx.x, tt = y - tbx.y;
            const float tr = tbx.z - xc, tb = tbx.w - y;

            const float pl = plv[k], pt = ptv[k], pr = prv[k], pb = pbv[k];

            const float w_i = fminf(pl, tl) + fminf(pr, tr);
            const float h_i = fminf(pt, tt) + fminf(pb, tb);
            const float a_i = fmaxf(w_i, 0.0f) * fmaxf(h_i, 0.0f);
            const float a_p = (pl + pr) * (pt + pb);
            const float a_t = (tl + tr) * (tt + tb);
            const float a_u = a_p + a_t - a_i + 1e-7f;
            const float iou_raw = a_i / a_u;

            const float w_e = fmaxf(pl, tl) + fmaxf(pr, tr);
            const float h_e = fmaxf(pt, tt) + fmaxf(pb, tb);
            const float a_e = fmaxf(w_e, 0.0f) * fmaxf(h_e, 0.0f) + 1e-7f;
            const float gl = 1.0f - (iou_raw - (a_e - a_u) / a_e);

            regl += pos ? gl : 0.0f;
            posf += pos ? 1.0f : 0.0f;
            const float gt_iou = pos ? fminf(fmaxf(iou_raw, 0.0f), 1.0f) : 0.0f;

            const float logit = lgv[k];
            const float p = 1.0f / (1.0f + expf(-logit));
            const float log_p  = logsig(logit);
            const float log_np = logsig(-logit);
            if (gt_iou > 0.0f)
                clsl += -gt_iou * (gt_iou * log_p + (1.0f - gt_iou) * log_np);
            else
                clsl += -0.75f * p * p * log_np;
        }
    }

    // block reduction: wave shuffle (width 64) then cross-wave via LDS
    float v0 = clsl, v1 = regl, v2 = posf;
    #pragma unroll
    for (int off = 32; off > 0; off >>= 1) {
        v0 += __shfl_down(v0, off);
        v1 += __shfl_down(v1, off);
        v2 += __shfl_down(v2, off);
    }
    __shared__ float red[3][TPB / 64];
    const int lane = threadIdx.x & 63;
    const int wv   = threadIdx.x >> 6;
    if (lane == 0) { red[0][wv] = v0; red[1][wv] = v1; red[2][wv] = v2; }
    __syncthreads();
    if (threadIdx.x == 0) {
        float s0 = 0, s1 = 0, s2 = 0;
        #pragma unroll
        for (int wvi = 0; wvi < TPB / 64; ++wvi) { s0 += red[0][wvi]; s1 += red[1][wvi]; s2 += red[2][wvi]; }
        // plain stores to distinct addresses -- no serialization, no atomics
        const int p = blockIdx.y * GX + blockIdx.x;
        part[p]             = s0;
        part[NPART + p]     = s1;
        part[2 * NPART + p] = s2;
    }
}

__global__ __launch_bounds__(TPB) void fcos_final(
    const float* __restrict__ part, float* __restrict__ out, int B)
{
    float s0 = 0.0f, s1 = 0.0f, s2 = 0.0f;
    for (int i = threadIdx.x; i < NPART; i += TPB) {
        s0 += part[i];
        s1 += part[NPART + i];
        s2 += part[2 * NPART + i];
    }
    #pragma unroll
    for (int off = 32; off > 0; off >>= 1) {
        s0 += __shfl_down(s0, off);
        s1 += __shfl_down(s1, off);
        s2 += __shfl_down(s2, off);
    }
    __shared__ float red[3][TPB / 64];
    const int lane = threadIdx.x & 63;
    const int wv   = threadIdx.x >> 6;
    if (lane == 0) { red[0][wv] = s0; red[1][wv] = s1; red[2][wv] = s2; }
    __syncthreads();
    if (threadIdx.x == 0) {
        float cls_sum = 0, reg_sum = 0, npos = 0;
        #pragma unroll
        for (int wvi = 0; wvi < TPB / 64; ++wvi) {
            cls_sum += red[0][wvi]; reg_sum += red[1][wvi]; npos += red[2][wvi];
        }
        const float navg = fmaxf(1.0f, npos / (float)B);
        out[0] = (cls_sum + reg_sum) / navg;
        out[1] = cls_sum / navg;
        out[2] = reg_sum / navg;
    }
}

extern "C" void kernel_launch(void* const* d_in, const int* in_sizes, int n_in,
                              void* d_out, int out_size, void* d_ws, size_t ws_size,
                              hipStream_t stream) {
    const float* cls0 = (const float*)d_in[0];
    const float* cls1 = (const float*)d_in[1];
    const float* cls2 = (const float*)d_in[2];
    const float* reg0 = (const float*)d_in[3];
    const float* reg1 = (const float*)d_in[4];
    const float* reg2 = (const float*)d_in[5];
    const float* boxes = (const float*)d_in[6];

    const int B = in_sizes[0] / NL0;          // 16
    const int M = in_sizes[6] / (4 * B);      // 64 (<= MAXM)

    float* part = (float*)d_ws;               // 3 * NPART floats

    dim3 grid(GX, B);
    fcos_main<<<grid, TPB, 0, stream>>>(cls0, cls1, cls2, reg0, reg1, reg2,
                                        boxes, M, part);
    fcos_final<<<1, TPB, 0, stream>>>(part, (float*)d_out, B);
}